// Round 4
// baseline (725.410 us; speedup 1.0000x reference)
//
#include <hip/hip_runtime.h>

// Router_26817775796684 — MI355X/gfx950, round 4.
// conv3x3(SAME)+relu+meanpool+fc+softmax+adaptive-threshold+sigmoid-renorm, fused.
//
// Round-4 changes (vs round 3):
//   * __launch_bounds__(256,3): unified reg budget 170/wave (need ~150: 64 acc +
//     ~85 arch). Round 3's (256,4) forced a 128 budget -> ~26 spilled regs ->
//     90 MB of scratch HBM traffic (the whole regression). 3 waves/EU = 12/CU.
//   * A-frag addresses: apos[t] = apos[0] + 2880*t (affine in t) -> one VALU add
//     per chunk + immediate ds_read offsets, instead of 4 address adds.
//   * Staging uses all 4 waves (sample = w>>1, ci-half = w&1); round 3 idled
//     waves 2-3 through the whole staging phase.
//   * Everything else identical (verified-correct math path, absmax 9.8e-4).

typedef _Float16 half8 __attribute__((ext_vector_type(8)));
typedef float    floatx4 __attribute__((ext_vector_type(4)));

#define A_SAMPLE  14400              // 100 rows * 144 B
#define LDS_P_OFF 28800              // pooled[2][128] fp32 after 2 A samples
#define LDS_TOTAL 29824

__global__ void prep_weights(const float* __restrict__ cw, _Float16* __restrict__ Bw) {
  int i = blockIdx.x * 256 + threadIdx.x;   // 0 .. 128*672-1
  int co = i / 672;
  int k  = i - co * 672;
  int s  = k / 72;                          // shift index (9 real, 9 = tail pad)
  int ci = k - s * 72;
  float v = 0.f;
  if (s < 9 && ci < 68) {
    int ky = s / 3, kx = s - 3 * ky;
    v = cw[((co * 68 + ci) * 3 + ky) * 3 + kx];
  }
  Bw[i] = (_Float16)v;                      // pads are EXACT zeros (never NaN)
}

__global__ __launch_bounds__(256, 3) void router_main(
    const float* __restrict__ patch,
    const float* __restrict__ conv_b,
    const _Float16* __restrict__ Bw,
    const float* __restrict__ fc_w,
    const float* __restrict__ fc_b,
    const float* __restrict__ p_wmax,
    const float* __restrict__ p_went,
    const float* __restrict__ p_wgap,
    const float* __restrict__ p_thr,
    const int* __restrict__ p_epoch,
    float* __restrict__ out)
{
  __shared__ __align__(16) unsigned char lds[LDS_TOTAL];
  const int tid    = threadIdx.x;
  const int l      = tid & 63;
  const int w      = tid >> 6;      // wave 0..3
  const int lane15 = l & 15;
  const int quad   = l >> 4;
  const int smp    = w >> 1;        // this wave's sample (0/1)
  const int n0     = (w & 1) * 64;  // N 64-half
  const int n_s    = blockIdx.x * 2;

  // ---- cooperative zero-fill of both padded A regions (borders become zeros) ----
  {
    float4 z4 = make_float4(0.f, 0.f, 0.f, 0.f);
    #pragma unroll
    for (int j = 0; j < 8; ++j) {
      int idx = j * 256 + tid;              // 1800 float4 slots total
      if (idx < 1800) *(float4*)(lds + idx * 16) = z4;
    }
  }
  __syncthreads();
  // ---- stage interiors: wave w -> sample (w>>1), ci-half (w&1); lane = position ----
  {
    const int ss = w >> 1;                  // sample this wave stages
    const int hh = w & 1;                   // ci-block half: 0 -> blocks 0..4, 1 -> 5..8
    const int b0 = hh * 5, b1 = hh ? 9 : 5;
    const float* psrc = patch + (size_t)(n_s + ss) * 4352 + l;   // [ci][p] layout
    int y = l >> 3, x = l & 7;
    unsigned char* arow = lds + ss * A_SAMPLE + ((y + 1) * 10 + (x + 1)) * 144;
    for (int b = b0; b < b1; ++b) {         // ci-blocks of 8 (68 real + 4 zero pad)
      half8 h;
      #pragma unroll
      for (int j = 0; j < 8; ++j) {
        int ci = b * 8 + j;
        float v = (ci < 68) ? psrc[ci * 64] : 0.f;   // 256 B/wave coalesced
        h[j] = (_Float16)v;
      }
      *(half8*)(arow + b * 16) = h;
    }
  }
  __syncthreads();

  // ---- A fragment base: apos[t] = abase + 2880*t (affine in t) ----
  const unsigned char* abase;
  {
    int pp0 = ((lane15 >> 3) + 1) * 10 + (lane15 & 7) + 1;   // padded row of p = lane15
    abase = lds + smp * A_SAMPLE + pp0 * 144;
  }

  // ---- B gather pointers (per-lane; 172 KB table is L2-resident) ----
  const _Float16* bptr[4];
  #pragma unroll
  for (int n = 0; n < 4; ++n)
    bptr[n] = Bw + (size_t)(n0 + n * 16 + lane15) * 672 + quad * 8;

  floatx4 acc[4][4];
  floatx4 zacc = {0.f, 0.f, 0.f, 0.f};
  #pragma unroll
  for (int t = 0; t < 4; ++t)
    #pragma unroll
    for (int n = 0; n < 4; ++n) acc[t][n] = zacc;

  half8 b0r[4], b1r[4];
  #pragma unroll
  for (int n = 0; n < 4; ++n) b0r[n] = *(const half8*)(bptr[n]);  // chunk 0

  // ---- barrier-free K loop: chunks 0..19 in pairs (b0r/b1r alternate, no copies) ----
  #pragma unroll
  for (int cc = 0; cc < 10; ++cc) {
    const int c0 = 2 * cc, c1 = 2 * cc + 1, c2 = 2 * cc + 2;    // c2 <= 20
    #pragma unroll
    for (int n = 0; n < 4; ++n)
      b1r[n] = *(const half8*)(bptr[n] + c1 * 32);

    {
      int kb  = c0 * 4 + quad;
      int s   = (kb * 57) >> 9;           // kb/9, exact for 0..83
      int rem = kb - s * 9;
      int dy  = (s * 11) >> 5;            // s/3
      int dx  = s - 3 * dy;
      const unsigned char* ap = abase + (dy * 10 + dx - 11) * 144 + rem * 16;
      half8 afr[4];
      #pragma unroll
      for (int t = 0; t < 4; ++t)
        afr[t] = *(const half8*)(ap + t * 2880);     // imm ds offsets 0/2880/5760/8640
      #pragma unroll
      for (int t = 0; t < 4; ++t)
        #pragma unroll
        for (int n = 0; n < 4; ++n)
          acc[t][n] = __builtin_amdgcn_mfma_f32_16x16x32_f16(afr[t], b0r[n], acc[t][n], 0, 0, 0);
    }

    #pragma unroll
    for (int n = 0; n < 4; ++n)
      b0r[n] = *(const half8*)(bptr[n] + c2 * 32);

    {
      int kb  = c1 * 4 + quad;
      int s   = (kb * 57) >> 9;
      int rem = kb - s * 9;
      int dy  = (s * 11) >> 5;
      int dx  = s - 3 * dy;
      const unsigned char* ap = abase + (dy * 10 + dx - 11) * 144 + rem * 16;
      half8 afr[4];
      #pragma unroll
      for (int t = 0; t < 4; ++t)
        afr[t] = *(const half8*)(ap + t * 2880);
      #pragma unroll
      for (int t = 0; t < 4; ++t)
        #pragma unroll
        for (int n = 0; n < 4; ++n)
          acc[t][n] = __builtin_amdgcn_mfma_f32_16x16x32_f16(afr[t], b1r[n], acc[t][n], 0, 0, 0);
    }
  }

  // ---- peeled tail chunk c=20 (in b0r): kb=80 (quad 0) real; kb 81..83 hit
  //      exact-zero B columns, A offset clamped in-bounds (finite data). ----
  {
    const unsigned char* ap = abase + ((quad == 0) ? 1712 : 0);
    half8 afr[4];
    #pragma unroll
    for (int t = 0; t < 4; ++t)
      afr[t] = *(const half8*)(ap + t * 2880);
    #pragma unroll
    for (int t = 0; t < 4; ++t)
      #pragma unroll
      for (int n = 0; n < 4; ++n)
        acc[t][n] = __builtin_amdgcn_mfma_f32_16x16x32_f16(afr[t], b0r[n], acc[t][n], 0, 0, 0);
  }

  // ---- bias + relu + mean-pool (C layout: row = quad*4+reg, col = lane15) ----
  float bcoef[4];
  #pragma unroll
  for (int n = 0; n < 4; ++n) bcoef[n] = conv_b[n0 + n * 16 + lane15];

  float* pl = (float*)(lds + LDS_P_OFF);          // pooled[2][128]
  #pragma unroll
  for (int n = 0; n < 4; ++n) {
    float ssum = 0.f;
    #pragma unroll
    for (int t = 0; t < 4; ++t)
      #pragma unroll
      for (int r = 0; r < 4; ++r)
        ssum += fmaxf(acc[t][n][r] + bcoef[n], 0.f);
    ssum += __shfl_xor(ssum, 16);                 // sum the 4 quad partials
    ssum += __shfl_xor(ssum, 32);
    if (l < 16)
      pl[smp * 128 + n0 + n * 16 + lane15] = ssum * (1.f / 64.f);
  }
  __syncthreads();

  // ---- fused routing epilogue: waves 0,1 handle samples 0,1 ----
  if (w < 2) {
    const float* plw = pl + w * 128;
    int e  = l >> 3;                                 // expert 0..7
    int c8 = l & 7;
    float part = 0.f;
    #pragma unroll
    for (int m = 0; m < 16; ++m) {
      int co = c8 + 8 * m;
      part += plw[co] * fc_w[co * 8 + e];
    }
    part += __shfl_xor(part, 1);
    part += __shfl_xor(part, 2);
    part += __shfl_xor(part, 4);

    float lg[8];
    #pragma unroll
    for (int j = 0; j < 8; ++j) lg[j] = __shfl(part, j * 8) + fc_b[j];

    float mx = lg[0];
    #pragma unroll
    for (int j = 1; j < 8; ++j) mx = fmaxf(mx, lg[j]);
    float wgt[8]; float sum = 0.f;
    #pragma unroll
    for (int j = 0; j < 8; ++j) { wgt[j] = expf(lg[j] - mx); sum += wgt[j]; }
    float inv = 1.f / sum;
    #pragma unroll
    for (int j = 0; j < 8; ++j) wgt[j] *= inv;

    // sort descending — Batcher odd-even, 19 comparators
    float sw[8];
    #pragma unroll
    for (int j = 0; j < 8; ++j) sw[j] = wgt[j];
    #define CSD(i, j) { float hi_ = fmaxf(sw[i], sw[j]); float lo_ = fminf(sw[i], sw[j]); sw[i] = hi_; sw[j] = lo_; }
    CSD(0,1) CSD(2,3) CSD(4,5) CSD(6,7)
    CSD(0,2) CSD(1,3) CSD(4,6) CSD(5,7)
    CSD(1,2) CSD(5,6)
    CSD(0,4) CSD(1,5) CSD(2,6) CSD(3,7)
    CSD(2,4) CSD(3,5)
    CSD(1,2) CSD(3,4) CSD(5,6)
    #undef CSD

    float s1 = 0.f;
    #pragma unroll
    for (int j = 0; j < 8; ++j) s1 += wgt[j];
    float mean = s1 * 0.125f;
    float var = 0.f;
    #pragma unroll
    for (int j = 0; j < 8; ++j) { float d = wgt[j] - mean; var += d * d; }
    float stdv = sqrtf(var * (1.f / 7.f));          // ddof=1
    float ent = 0.f;
    #pragma unroll
    for (int j = 0; j < 8; ++j) ent -= wgt[j] * logf(wgt[j] + 1e-18f);

    float maxc  = 1.f - sw[0];
    float entc  = 1.f - ent * 0.48089834696298783f; // 1/log(8)
    float mrest = (sw[1] + sw[2] + sw[3] + sw[4]) * 0.25f;
    float gap   = (sw[0] - mrest) / (sw[0] + 1e-8f);
    gap = fminf(fmaxf(gap, 0.f), 1.f);
    float af = p_wmax[0] * maxc + p_went[0] * entc + p_wgap[0] * gap;
    float th = p_thr[0] * (0.5f + af);
    float mn  = fmaxf(0.05f, mean - 0.5f * stdv);
    float mxt = fminf(0.7f, sw[0] - 0.1f * stdv);
    th = fminf(fmaxf(th, mn), mxt);                 // jnp.clip: lower then upper
    th = fminf(th, sw[1] * 0.9f);                   // kth = sw[MIN_EXPERTS_ACTIVE-1]

    int epoch = p_epoch[0];
    float outv[8];
    if (epoch < 20) {
      #pragma unroll
      for (int j = 0; j < 8; ++j) outv[j] = 0.125f;
    } else {
      float tau = (epoch <= 25) ? fmaxf(0.1f, 1.0f - (float)(epoch - 20) * 0.18f) : 0.1f;
      // forward value of hard + stopgrad(soft-hard) == soft exactly
      float ssum = 0.f;
      #pragma unroll
      for (int j = 0; j < 8; ++j) {
        float sj = 1.f / (1.f + expf(-(wgt[j] - th) / tau));
        outv[j] = sj; ssum += sj;
      }
      float invs = 1.f / fmaxf(ssum, 1e-8f);
      #pragma unroll
      for (int j = 0; j < 8; ++j) outv[j] *= invs;
    }

    if (l < 8) {
      float mv = outv[0];
      #pragma unroll
      for (int j = 1; j < 8; ++j) mv = (l == j) ? outv[j] : mv;
      out[(n_s + w) * 8 + l] = mv;
    }
  }
}

extern "C" void kernel_launch(void* const* d_in, const int* in_sizes, int n_in,
                              void* d_out, int out_size, void* d_ws, size_t ws_size,
                              hipStream_t stream) {
  const float* patch  = (const float*)d_in[0];
  const float* conv_w = (const float*)d_in[1];
  const float* conv_b = (const float*)d_in[2];
  const float* fc_w   = (const float*)d_in[3];
  const float* fc_b   = (const float*)d_in[4];
  const float* wmax   = (const float*)d_in[5];
  const float* went   = (const float*)d_in[6];
  const float* wgap   = (const float*)d_in[7];
  const float* thr    = (const float*)d_in[8];
  const int*   epoch  = (const int*)d_in[10];
  float* outp = (float*)d_out;
  _Float16* Bw = (_Float16*)d_ws;                 // 128*672*2 = 172,032 B of ws

  int N = in_sizes[0] / 4352;                     // 16384 samples
  prep_weights<<<336, 256, 0, stream>>>(conv_w, Bw);
  router_main<<<N / 2, 256, 0, stream>>>(patch, conv_b, Bw, fc_w, fc_b,
                                         wmax, went, wgap, thr, epoch, outp);
}

// Round 5
// 507.753 us; speedup vs baseline: 1.4287x; 1.4287x over previous
//
#include <hip/hip_runtime.h>

// Router_26817775796684 — MI355X/gfx950, round 5.
// conv3x3(SAME)+relu+meanpool+fc+softmax+adaptive-threshold+sigmoid-renorm, fused.
//
// Round-5: back to the round-2 shape (WG=4 samples, wave tile M=128xN=64,
// launch_bounds(256,2) => 256-reg budget, no spill, 2 WG/CU) — rounds 3/4 proved
// M=64 waves can't hide the per-lane B-gather L2 latency (MfmaUtil 16-25%).
// New: 32x32x16 f16 MFMA (16384 MACs/instr, ~99.8%-of-peak shape per m119) —
// MFMA pipe floor 87 -> 72 us; same LDS traffic; pair-unrolled b0/b1 B prefetch
// (no mov chain); affine A addressing (imm ds offsets); tail chunk = mi=0 only.
//
// Layouts (32x32x16): A[m=lane&31][k=(lane>>5)*8+j] (extrapolated from verified
// 16x16 rule); C/D col=lane&31, row=(reg&3)+8*(reg>>2)+4*(lane>>5) (HW-verified).

typedef _Float16 half8 __attribute__((ext_vector_type(8)));
typedef float    floatx16 __attribute__((ext_vector_type(16)));

#define A_SAMPLE  14400              // 100 rows * 144 B
#define LDS_P_OFF 57600              // pooled[4][128] fp32 after 4 A samples
#define LDS_TOTAL 59648

__global__ void prep_weights(const float* __restrict__ cw, _Float16* __restrict__ Bw) {
  int i = blockIdx.x * 256 + threadIdx.x;   // 0 .. 128*672-1
  int co = i / 672;
  int k  = i - co * 672;
  int s  = k / 72;                          // shift index (9 real, 9 = tail pad)
  int ci = k - s * 72;
  float v = 0.f;
  if (s < 9 && ci < 68) {
    int ky = s / 3, kx = s - 3 * ky;
    v = cw[((co * 68 + ci) * 3 + ky) * 3 + kx];
  }
  Bw[i] = (_Float16)v;                      // pads are EXACT zeros (never NaN)
}

__device__ __forceinline__ int shift_roff(int kb) {
  // kb (0..83) -> byte offset of the shifted row start + ci-block offset
  int s   = (kb * 57) >> 9;           // kb/9, exact for 0..83
  int rem = kb - s * 9;
  int dy  = (s * 11) >> 5;            // s/3
  int dx  = s - 3 * dy;
  return (dy * 10 + dx - 11) * 144 + rem * 16;
}

__global__ __launch_bounds__(256, 2) void router_main(
    const float* __restrict__ patch,
    const float* __restrict__ conv_b,
    const _Float16* __restrict__ Bw,
    const float* __restrict__ fc_w,
    const float* __restrict__ fc_b,
    const float* __restrict__ p_wmax,
    const float* __restrict__ p_went,
    const float* __restrict__ p_wgap,
    const float* __restrict__ p_thr,
    const int* __restrict__ p_epoch,
    float* __restrict__ out)
{
  __shared__ __align__(16) unsigned char lds[LDS_TOTAL];
  const int tid    = threadIdx.x;
  const int l      = tid & 63;
  const int w      = tid >> 6;      // wave 0..3
  const int lane31 = l & 31;
  const int bhalf  = l >> 5;        // k-half within an MFMA (0/1)
  const int m_half = w >> 1;        // which sample-pair this wave computes
  const int n0     = (w & 1) * 64;  // N 64-half
  const int n_s    = blockIdx.x * 4;

  // ---- zero-fill own sample's padded A region (borders become zeros) ----
  {
    unsigned char* abase0 = lds + w * A_SAMPLE;
    float4 z4 = make_float4(0.f, 0.f, 0.f, 0.f);
    #pragma unroll
    for (int j = 0; j < 15; ++j) {
      int idx = j * 64 + l;                 // 900 b128 slots per sample
      if (idx < 900) *(float4*)(abase0 + idx * 16) = z4;
    }
  }
  // ---- stage interior: lane l = position p=(y,x) -> padded row (y+1)*10+(x+1) ----
  // (DS ops from one wave process in order: fill-then-write is safe.)
  {
    const float* psrc = patch + (size_t)(n_s + w) * 4352 + l;   // [ci][p] layout
    int y = l >> 3, x = l & 7;
    unsigned char* arow = lds + w * A_SAMPLE + ((y + 1) * 10 + (x + 1)) * 144;
    #pragma unroll
    for (int b = 0; b < 9; ++b) {           // 9 ci-blocks of 8 (68 real + 4 zero pad)
      half8 h;
      #pragma unroll
      for (int j = 0; j < 8; ++j) {
        int ci = b * 8 + j;
        float v = (ci < 68) ? psrc[ci * 64] : 0.f;   // 256 B/wave coalesced
        h[j] = (_Float16)v;
      }
      *(half8*)(arow + b * 16) = h;
    }
  }
  __syncthreads();

  // ---- A base: tile mt reads row of position p = mt*32 + lane31 (affine in mt):
  //      apos[mt] = abase + (mt&1)*5760 + (mt>>1)*14400  (fold to imm offsets) ----
  const unsigned char* abase;
  {
    int pp0 = ((lane31 >> 3) + 1) * 10 + (lane31 & 7) + 1;   // padded row, y in 0..3
    abase = lds + (m_half * 2) * A_SAMPLE + pp0 * 144;
  }

  // ---- B gather pointers: co = n0 + nt*32 + lane31, lane k-half at bhalf*8.
  //      chunk c, k-sub mi: bytes bp[nt] + c*64 + mi*32 (imm offsets) ----
  const _Float16* bp[2];
  #pragma unroll
  for (int nt = 0; nt < 2; ++nt)
    bp[nt] = Bw + (size_t)(n0 + nt * 32 + lane31) * 672 + bhalf * 8;

  floatx16 acc[4][2];                 // [mt][nt]
  #pragma unroll
  for (int mt = 0; mt < 4; ++mt)
    #pragma unroll
    for (int nt = 0; nt < 2; ++nt)
      #pragma unroll
      for (int r = 0; r < 16; ++r) acc[mt][nt][r] = 0.f;

  // B frag buffers: index [mi*2+nt]
  half8 bA[4], bB[4];
  #pragma unroll
  for (int mi = 0; mi < 2; ++mi)
    #pragma unroll
    for (int nt = 0; nt < 2; ++nt)
      bA[mi * 2 + nt] = *(const half8*)(bp[nt] + mi * 16);   // chunk 0

  #define COMPUTE_CHUNK(c, B)                                                     \
  {                                                                               \
    int roff0 = shift_roff((c) * 4 + bhalf);        /* mi=0 */                    \
    int roff1 = shift_roff((c) * 4 + 2 + bhalf);    /* mi=1 */                    \
    const unsigned char* ap0 = abase + roff0;                                     \
    const unsigned char* ap1 = abase + roff1;                                     \
    half8 a0[4], a1[4];                                                           \
    _Pragma("unroll")                                                             \
    for (int mt = 0; mt < 4; ++mt)                                                \
      a0[mt] = *(const half8*)(ap0 + (mt & 1) * 5760 + (mt >> 1) * 14400);        \
    _Pragma("unroll")                                                             \
    for (int mt = 0; mt < 4; ++mt)                                                \
      a1[mt] = *(const half8*)(ap1 + (mt & 1) * 5760 + (mt >> 1) * 14400);        \
    _Pragma("unroll")                                                             \
    for (int mt = 0; mt < 4; ++mt)                                                \
      _Pragma("unroll")                                                           \
      for (int nt = 0; nt < 2; ++nt)                                              \
        acc[mt][nt] = __builtin_amdgcn_mfma_f32_32x32x16_f16(a0[mt], B[nt],       \
                                                             acc[mt][nt], 0, 0, 0); \
    _Pragma("unroll")                                                             \
    for (int mt = 0; mt < 4; ++mt)                                                \
      _Pragma("unroll")                                                           \
      for (int nt = 0; nt < 2; ++nt)                                              \
        acc[mt][nt] = __builtin_amdgcn_mfma_f32_32x32x16_f16(a1[mt], B[2 + nt],   \
                                                             acc[mt][nt], 0, 0, 0); \
  }

  // ---- barrier-free K loop: chunks 0..19 in pairs (bA/bB alternate) ----
  #pragma unroll
  for (int cc = 0; cc < 10; ++cc) {
    const int c0 = 2 * cc, c1 = 2 * cc + 1, c2 = 2 * cc + 2;   // c2 <= 20
    #pragma unroll
    for (int mi = 0; mi < 2; ++mi)
      #pragma unroll
      for (int nt = 0; nt < 2; ++nt)
        bB[mi * 2 + nt] = *(const half8*)(bp[nt] + c1 * 32 + mi * 16);
    COMPUTE_CHUNK(c0, bA)
    #pragma unroll
    for (int mi = 0; mi < 2; ++mi)
      #pragma unroll
      for (int nt = 0; nt < 2; ++nt)
        bA[mi * 2 + nt] = *(const half8*)(bp[nt] + c2 * 32 + mi * 16);
    COMPUTE_CHUNK(c1, bB)
  }
  #undef COMPUTE_CHUNK

  // ---- tail chunk c=20, mi=0 only: kb = 80+bhalf. kb=80 real (roff 1712),
  //      kb=81 hits exact-zero B rows (A clamped in-bounds); kb 82/83 (mi=1)
  //      are all-zero B frags -> skip those 8 MFMAs entirely. ----
  {
    const unsigned char* ap = abase + ((bhalf == 0) ? 1712 : 0);
    half8 at[4];
    #pragma unroll
    for (int mt = 0; mt < 4; ++mt)
      at[mt] = *(const half8*)(ap + (mt & 1) * 5760 + (mt >> 1) * 14400);
    #pragma unroll
    for (int mt = 0; mt < 4; ++mt)
      #pragma unroll
      for (int nt = 0; nt < 2; ++nt)
        acc[mt][nt] = __builtin_amdgcn_mfma_f32_32x32x16_f16(at[mt], bA[nt],
                                                             acc[mt][nt], 0, 0, 0);
  }

  // ---- bias + relu + mean-pool.
  //      C/D 32x32 layout: col = lane31, row m = (reg&3) + 8*(reg>>2) + 4*bhalf.
  //      Lane sums its 16 rows; lane^32 holds the complementary 16 -> xor(32). ----
  float bco[2];
  #pragma unroll
  for (int nt = 0; nt < 2; ++nt) bco[nt] = conv_b[n0 + nt * 32 + lane31];

  float* pl = (float*)(lds + LDS_P_OFF);          // pooled[4][128]
  #pragma unroll
  for (int g = 0; g < 2; ++g) {                   // sample within this wave's pair
    #pragma unroll
    for (int nt = 0; nt < 2; ++nt) {
      float ssum = 0.f;
      #pragma unroll
      for (int mh = 0; mh < 2; ++mh) {            // tiles 2g, 2g+1
        #pragma unroll
        for (int r = 0; r < 16; ++r)
          ssum += fmaxf(acc[g * 2 + mh][nt][r] + bco[nt], 0.f);
      }
      ssum += __shfl_xor(ssum, 32);               // complete the 32-row sums
      if (l < 32)
        pl[(m_half * 2 + g) * 128 + n0 + nt * 32 + lane31] = ssum * (1.f / 64.f);
    }
  }
  __syncthreads();

  // ---- fused routing epilogue: wave w handles sample (n_s + w) ----
  const float* plw = pl + w * 128;
  int e  = l >> 3;                                 // expert 0..7
  int c8 = l & 7;
  float part = 0.f;
  #pragma unroll
  for (int m = 0; m < 16; ++m) {
    int co = c8 + 8 * m;
    part += plw[co] * fc_w[co * 8 + e];
  }
  part += __shfl_xor(part, 1);
  part += __shfl_xor(part, 2);
  part += __shfl_xor(part, 4);

  float lg[8];
  #pragma unroll
  for (int j = 0; j < 8; ++j) lg[j] = __shfl(part, j * 8) + fc_b[j];

  float mx = lg[0];
  #pragma unroll
  for (int j = 1; j < 8; ++j) mx = fmaxf(mx, lg[j]);
  float wgt[8]; float sum = 0.f;
  #pragma unroll
  for (int j = 0; j < 8; ++j) { wgt[j] = expf(lg[j] - mx); sum += wgt[j]; }
  float inv = 1.f / sum;
  #pragma unroll
  for (int j = 0; j < 8; ++j) wgt[j] *= inv;

  // sort descending — Batcher odd-even, 19 comparators
  float sw[8];
  #pragma unroll
  for (int j = 0; j < 8; ++j) sw[j] = wgt[j];
  #define CSD(i, j) { float hi_ = fmaxf(sw[i], sw[j]); float lo_ = fminf(sw[i], sw[j]); sw[i] = hi_; sw[j] = lo_; }
  CSD(0,1) CSD(2,3) CSD(4,5) CSD(6,7)
  CSD(0,2) CSD(1,3) CSD(4,6) CSD(5,7)
  CSD(1,2) CSD(5,6)
  CSD(0,4) CSD(1,5) CSD(2,6) CSD(3,7)
  CSD(2,4) CSD(3,5)
  CSD(1,2) CSD(3,4) CSD(5,6)
  #undef CSD

  float s1 = 0.f;
  #pragma unroll
  for (int j = 0; j < 8; ++j) s1 += wgt[j];
  float mean = s1 * 0.125f;
  float var = 0.f;
  #pragma unroll
  for (int j = 0; j < 8; ++j) { float d = wgt[j] - mean; var += d * d; }
  float stdv = sqrtf(var * (1.f / 7.f));          // ddof=1
  float ent = 0.f;
  #pragma unroll
  for (int j = 0; j < 8; ++j) ent -= wgt[j] * logf(wgt[j] + 1e-18f);

  float maxc  = 1.f - sw[0];
  float entc  = 1.f - ent * 0.48089834696298783f; // 1/log(8)
  float mrest = (sw[1] + sw[2] + sw[3] + sw[4]) * 0.25f;
  float gap   = (sw[0] - mrest) / (sw[0] + 1e-8f);
  gap = fminf(fmaxf(gap, 0.f), 1.f);
  float af = p_wmax[0] * maxc + p_went[0] * entc + p_wgap[0] * gap;
  float th = p_thr[0] * (0.5f + af);
  float mn  = fmaxf(0.05f, mean - 0.5f * stdv);
  float mxt = fminf(0.7f, sw[0] - 0.1f * stdv);
  th = fminf(fmaxf(th, mn), mxt);                 // jnp.clip: lower then upper
  th = fminf(th, sw[1] * 0.9f);                   // kth = sw[MIN_EXPERTS_ACTIVE-1]

  int epoch = p_epoch[0];
  float outv[8];
  if (epoch < 20) {
    #pragma unroll
    for (int j = 0; j < 8; ++j) outv[j] = 0.125f;
  } else {
    float tau = (epoch <= 25) ? fmaxf(0.1f, 1.0f - (float)(epoch - 20) * 0.18f) : 0.1f;
    // forward value of hard + stopgrad(soft-hard) == soft exactly
    float ssum = 0.f;
    #pragma unroll
    for (int j = 0; j < 8; ++j) {
      float sj = 1.f / (1.f + expf(-(wgt[j] - th) / tau));
      outv[j] = sj; ssum += sj;
    }
    float invs = 1.f / fmaxf(ssum, 1e-8f);
    #pragma unroll
    for (int j = 0; j < 8; ++j) outv[j] *= invs;
  }

  if (l < 8) {
    float mv = outv[0];
    #pragma unroll
    for (int j = 1; j < 8; ++j) mv = (l == j) ? outv[j] : mv;
    out[(n_s + w) * 8 + l] = mv;
  }
}

extern "C" void kernel_launch(void* const* d_in, const int* in_sizes, int n_in,
                              void* d_out, int out_size, void* d_ws, size_t ws_size,
                              hipStream_t stream) {
  const float* patch  = (const float*)d_in[0];
  const float* conv_w = (const float*)d_in[1];
  const float* conv_b = (const float*)d_in[2];
  const float* fc_w   = (const float*)d_in[3];
  const float* fc_b   = (const float*)d_in[4];
  const float* wmax   = (const float*)d_in[5];
  const float* went   = (const float*)d_in[6];
  const float* wgap   = (const float*)d_in[7];
  const float* thr    = (const float*)d_in[8];
  const int*   epoch  = (const int*)d_in[10];
  float* outp = (float*)d_out;
  _Float16* Bw = (_Float16*)d_ws;                 // 128*672*2 = 172,032 B of ws

  int N = in_sizes[0] / 4352;                     // 16384 samples
  prep_weights<<<336, 256, 0, stream>>>(conv_w, Bw);
  router_main<<<N / 4, 256, 0, stream>>>(patch, conv_b, Bw, fc_w, fc_b,
                                         wmax, went, wgap, thr, epoch, outp);
}